// Round 7
// baseline (6701.584 us; speedup 1.0000x reference)
//
#include <hip/hip_runtime.h>
#include <hip/hip_fp16.h>

#define H     2048
#define LSEQ  512
#define NWG   256
#define TPB   512
#define UPW   8     // hidden units per WG
#define RPW   32    // gate rows per WG
#define KG    16    // k-groups per row

// ws float-index layout
#define WS_UA    0        // 512 floats
#define WS_HG    512      // 1024 uints = 2048 packed halfs (h state)
#define WS_GEN   1536     // 1 int
#define WS_FLAGS 1600     // 256*32 ints (128B-padded arrival flags)
#define WS_PH    16384    // P as half: 8192*512 halfs = 2M floats
#define WS_WHH   (WS_PH + 2097152)          // w_hh as half: 16M halfs = 8M floats
#define WS_NEED_BYTES (((size_t)WS_WHH + 8388608) * 4)   // ~42 MB

#define AT_LDF(p)    __hip_atomic_load((p),  __ATOMIC_RELAXED, __HIP_MEMORY_SCOPE_SYSTEM)
#define AT_STF(p, v) __hip_atomic_store((p), (v), __ATOMIC_RELAXED, __HIP_MEMORY_SCOPE_SYSTEM)
#define AT_LDI(p)    __hip_atomic_load((p),  __ATOMIC_RELAXED, __HIP_MEMORY_SCOPE_SYSTEM)
#define AT_LDU(p)    __hip_atomic_load((p),  __ATOMIC_RELAXED, __HIP_MEMORY_SCOPE_SYSTEM)
#define AT_STU(p, v) __hip_atomic_store((p), (v), __ATOMIC_RELAXED, __HIP_MEMORY_SCOPE_SYSTEM)

__device__ __forceinline__ float sigmoidf_(float v) { return 1.f / (1.f + __expf(-v)); }

// Zero-fence grid barrier (prologue only; the loop inlines it with h-publish).
// All cross-WG visibility via system-scope (sc0 sc1) atomics at the MALL.
// NO __threadfence: agent fences emit buffer_inv -> flush XCD L2 -> weights
// re-stream (R4's 60us/step). RELEASE stores only drain vmcnt (keep clean lines).
__device__ __forceinline__ void flag_barrier(int* flags, int* gen, int ep, int wg) {
  __syncthreads();
  if (wg == 0) {
    if (threadIdx.x > 0 && threadIdx.x < NWG) {
      while (AT_LDI(&flags[threadIdx.x * 32]) < ep) __builtin_amdgcn_s_sleep(2);
    }
    __syncthreads();
    if (threadIdx.x == 0)
      __hip_atomic_store(gen, ep, __ATOMIC_RELEASE, __HIP_MEMORY_SCOPE_SYSTEM);
  } else {
    if (threadIdx.x == 0) {
      __hip_atomic_store(&flags[wg * 32], ep, __ATOMIC_RELEASE, __HIP_MEMORY_SCOPE_SYSTEM);
      while (AT_LDI(gen) < ep) __builtin_amdgcn_s_sleep(2);
    }
    __syncthreads();
  }
}

__global__ void init_ws(float* ws) {
  int tid = threadIdx.x;
  for (int i = tid; i < 1024; i += 1024) ws[WS_HG + i] = 0.f;  // h0 = 0 (packed halfs)
  int* gen = (int*)(ws + WS_GEN);
  int* flags = (int*)(ws + WS_FLAGS);
  if (tid == 0) *gen = 0;
  for (int i = tid; i < NWG * 32; i += 1024) flags[i] = 0;
}

// ---- one-time: w_hh fp32 -> fp16 (layout unchanged) ----
__global__ __launch_bounds__(256) void whh_to_half(const float* __restrict__ src,
                                                   __half* __restrict__ dst) {
  size_t i = ((size_t)blockIdx.x * 256 + threadIdx.x) * 8;
  float4 a = *(const float4*)(src + i);
  float4 b = *(const float4*)(src + i + 4);
  __half2 o[4] = {__floats2half2_rn(a.x, a.y), __floats2half2_rn(a.z, a.w),
                  __floats2half2_rn(b.x, b.y), __floats2half2_rn(b.z, b.w)};
  *(float4*)(dst + i) = *(float4*)o;
}

// ---- one-time P = W_ih @ input^T -> half  ([8192,2048]x[512,2048]^T -> [8192,512]) ----
#define GP_BM 128
#define GP_BN 128
#define GP_BK 32
#define GP_PAD 5
__global__ __launch_bounds__(256) void gemm_P(const float* __restrict__ A,
                                              const float* __restrict__ B,
                                              __half* __restrict__ P) {
  __shared__ float As[GP_BM][GP_BK + GP_PAD];
  __shared__ float Bs[GP_BN][GP_BK + GP_PAD];
  const int tid = threadIdx.x;
  const int bm = blockIdx.x, bn = blockIdx.y;
  const int tr = tid >> 4, tc = tid & 15;
  float acc[8][8] = {};
  for (int k0 = 0; k0 < H; k0 += GP_BK) {
    #pragma unroll
    for (int i = 0; i < 4; ++i) {
      int lin = tid + 256 * i;
      int r = lin >> 3, c4 = lin & 7;
      float4 va = *(const float4*)(A + (size_t)(bm * GP_BM + r) * H + k0 + c4 * 4);
      float4 vb = *(const float4*)(B + (size_t)(bn * GP_BN + r) * H + k0 + c4 * 4);
      As[r][c4 * 4 + 0] = va.x; As[r][c4 * 4 + 1] = va.y;
      As[r][c4 * 4 + 2] = va.z; As[r][c4 * 4 + 3] = va.w;
      Bs[r][c4 * 4 + 0] = vb.x; Bs[r][c4 * 4 + 1] = vb.y;
      Bs[r][c4 * 4 + 2] = vb.z; Bs[r][c4 * 4 + 3] = vb.w;
    }
    __syncthreads();
    #pragma unroll 8
    for (int k = 0; k < GP_BK; ++k) {
      float a[8], b[8];
      #pragma unroll
      for (int i = 0; i < 8; ++i) a[i] = As[tr * 8 + i][k];
      #pragma unroll
      for (int j = 0; j < 8; ++j) b[j] = Bs[tc * 8 + j][k];
      #pragma unroll
      for (int i = 0; i < 8; ++i)
        #pragma unroll
        for (int j = 0; j < 8; ++j) acc[i][j] += a[i] * b[j];
    }
    __syncthreads();
  }
  #pragma unroll
  for (int i = 0; i < 8; ++i) {
    __half2 o[4];
    #pragma unroll
    for (int j2 = 0; j2 < 4; ++j2)
      o[j2] = __floats2half2_rn(acc[i][j2 * 2], acc[i][j2 * 2 + 1]);
    *(float4*)(P + (size_t)(bm * GP_BM + tr * 8 + i) * LSEQ + bn * GP_BN + tc * 8) = *(float4*)o;
  }
}

// ---------------- persistent main kernel ----------------
template <bool HW16>
__global__ __launch_bounds__(TPB, 2) void attn_rnn_main(
    const float* __restrict__ input, const float* __restrict__ bias_mat,
    const float* __restrict__ conv_w, const float* __restrict__ conv_b,
    const float* __restrict__ fc1_w, const float* __restrict__ fc1_b,
    const float* __restrict__ w_hh, const float* __restrict__ b_ih,
    const float* __restrict__ b_hh,
    const int* __restrict__ seq_len,
    float* __restrict__ out, float* __restrict__ ws)
{
  const int wg   = blockIdx.x;
  const int tid  = threadIdx.x;
  const int lane = tid & 63;
  const int wv   = tid >> 6;   // 0..7

  float*        uaG   = ws + WS_UA;
  unsigned int* hGu   = (unsigned int*)(ws + WS_HG);
  int*          genp  = (int*)(ws + WS_GEN);
  int*          flags = (int*)(ws + WS_FLAGS);
  const __half* Ph    = (const __half*)(ws + WS_PH);
  const __half* whhH  = (const __half*)(ws + WS_WHH);

  __shared__ float h_lds[H];
  __shared__ float attn_lds[LSEQ];
  __shared__ float ua_lds[LSEQ];
  __shared__ float b_lds[LSEQ];
  __shared__ float g_lds[RPW];
  __shared__ float red8[8];
  __shared__ float redm[8];
  __shared__ float reds[8];
  __shared__ float c_state[UPW];
  __shared__ float h_tmp[UPW];

  const int r_local = tid >> 4;       // 0..31 gate row within WG
  const int kg      = tid & 15;       // 0..15 k-group
  const int gt      = r_local >> 3;
  const int u       = r_local & 7;
  const int rg      = gt * H + wg * UPW + u;
  const float brow  = b_ih[rg] + b_hh[rg];
  const __half*  wrowH  = whhH + (size_t)rg * H;
  const float4*  wrow32 = (const float4*)(w_hh + (size_t)rg * H);
  const __half*  prow   = Ph + (size_t)rg * LSEQ;

  const float4 fw4 = ((const float4*)fc1_w)[tid];
  if (tid < UPW) c_state[tid] = 0.f;

  int ep = 0;

  // ---- ua[l] = input[l,:]·conv_w + conv_b  (WG owns l = 2wg, 2wg+1) ----
  const float cb = conv_b[0];
  #pragma unroll
  for (int li = 0; li < 2; ++li) {
    int l = wg * 2 + li;
    float4 rv = ((const float4*)(input + (size_t)l * H))[tid];
    float4 cv = ((const float4*)conv_w)[tid];
    float s = rv.x * cv.x + rv.y * cv.y + rv.z * cv.z + rv.w * cv.w;
    #pragma unroll
    for (int m = 32; m; m >>= 1) s += __shfl_xor(s, m);
    if (lane == 0) red8[wv] = s;
    __syncthreads();
    if (tid == 0) {
      float v = cb;
      #pragma unroll
      for (int q = 0; q < 8; ++q) v += red8[q];
      AT_STF(&uaG[l], v);
    }
    __syncthreads();
  }

  ++ep; flag_barrier(flags, genp, ep, wg);

  // step-invariant terms into LDS
  ua_lds[tid & (LSEQ - 1)] = AT_LDF(&uaG[tid & (LSEQ - 1)]);
  b_lds[tid & (LSEQ - 1)]  = bias_mat[tid & (LSEQ - 1)];
  __syncthreads();

  const int S = seq_len[0];
  const float fb = fc1_b[0];

  for (int t = 0; t < S; ++t) {
    // ---- issue weight prefetch FIRST (L2-hot after iter 0; hides under softmax) ----
    float4 wp[16];
    if constexpr (HW16) {
      #pragma unroll
      for (int m = 0; m < 16; ++m) wp[m] = *(const float4*)(wrowH + kg * 8 + 128 * m);
      #pragma unroll
      for (int m = 0; m < 16; ++m)
        asm volatile("" : "+v"(wp[m].x), "+v"(wp[m].y), "+v"(wp[m].z), "+v"(wp[m].w));
    }
    float4 pp[4];
    #pragma unroll
    for (int m = 0; m < 4; ++m) pp[m] = *(const float4*)(prow + kg * 8 + 128 * m);
    #pragma unroll
    for (int m = 0; m < 4; ++m)
      asm volatile("" : "+v"(pp[m].x), "+v"(pp[m].y), "+v"(pp[m].z), "+v"(pp[m].w));

    // ---- h (packed half) coherent load -> LDS fp32; fc1 partial dot ----
    unsigned int hu0 = AT_LDU(hGu + tid * 2);
    unsigned int hu1 = AT_LDU(hGu + tid * 2 + 1);
    float2 f01 = __half22float2(*(__half2*)&hu0);
    float2 f23 = __half22float2(*(__half2*)&hu1);
    h_lds[tid * 4 + 0] = f01.x; h_lds[tid * 4 + 1] = f01.y;
    h_lds[tid * 4 + 2] = f23.x; h_lds[tid * 4 + 3] = f23.y;
    float s = f01.x * fw4.x + f01.y * fw4.y + f23.x * fw4.z + f23.y * fw4.w;
    #pragma unroll
    for (int m = 32; m; m >>= 1) s += __shfl_xor(s, m);
    if (lane == 0) red8[wv] = s;
    __syncthreads();                                  // sync 1
    float w_a = fb;
    #pragma unroll
    for (int q = 0; q < 8; ++q) w_a += red8[q];       // redundant combine (identical order)

    // ---- softmax, wave-level online max+sum (one publish round) ----
    float v0 = ua_lds[tid] + w_a;
    float v = v0 > 0.f ? v0 : 0.01f * v0;             // leaky_relu(0.01)
    v += b_lds[tid];
    float mw = v;
    #pragma unroll
    for (int m = 32; m; m >>= 1) mw = fmaxf(mw, __shfl_xor(mw, m));
    float eW = __expf(v - mw);
    float sw = eW;
    #pragma unroll
    for (int m = 32; m; m >>= 1) sw += __shfl_xor(sw, m);
    if (lane == 0) { redm[wv] = mw; reds[wv] = sw; }
    __syncthreads();                                  // sync 2
    float M = redm[0];
    #pragma unroll
    for (int q = 1; q < 8; ++q) M = fmaxf(M, redm[q]);
    float Ssum = 0.f;
    #pragma unroll
    for (int q = 0; q < 8; ++q) Ssum += reds[q] * __expf(redm[q] - M);
    const float inv = 1.f / Ssum;
    attn_lds[tid] = eW * __expf(mw - M);
    __syncthreads();                                  // sync 3

    // ---- gates: whh·h + inv*(P·e), weights from prefetch regs ----
    float acc = 0.f;
    if constexpr (HW16) {
      #pragma unroll
      for (int m = 0; m < 16; ++m) {
        const __half2* hp = (const __half2*)&wp[m];
        const int k = kg * 8 + 128 * m;
        float4 h0 = *(const float4*)(h_lds + k);
        float4 h1 = *(const float4*)(h_lds + k + 4);
        float2 w0 = __half22float2(hp[0]);
        float2 w1 = __half22float2(hp[1]);
        float2 w2 = __half22float2(hp[2]);
        float2 w3 = __half22float2(hp[3]);
        acc += w0.x * h0.x + w0.y * h0.y + w1.x * h0.z + w1.y * h0.w;
        acc += w2.x * h1.x + w2.y * h1.y + w3.x * h1.z + w3.y * h1.w;
      }
    } else {
      #pragma unroll
      for (int m = 0; m < 32; ++m) {
        float4 wv4 = wrow32[kg + KG * m];
        const int k = kg * 4 + 64 * m;
        acc += wv4.x * h_lds[k] + wv4.y * h_lds[k + 1] + wv4.z * h_lds[k + 2] + wv4.w * h_lds[k + 3];
      }
    }
    float accp = 0.f;
    #pragma unroll
    for (int m = 0; m < 4; ++m) {
      const __half2* hp = (const __half2*)&pp[m];
      const int l = kg * 8 + 128 * m;
      float4 a0 = *(const float4*)(attn_lds + l);
      float4 a1 = *(const float4*)(attn_lds + l + 4);
      float2 p0 = __half22float2(hp[0]);
      float2 p1 = __half22float2(hp[1]);
      float2 p2 = __half22float2(hp[2]);
      float2 p3 = __half22float2(hp[3]);
      accp += p0.x * a0.x + p0.y * a0.y + p1.x * a0.z + p1.y * a0.w;
      accp += p2.x * a1.x + p2.y * a1.y + p3.x * a1.z + p3.y * a1.w;
    }
    acc += accp * inv;
    acc += __shfl_xor(acc, 1);
    acc += __shfl_xor(acc, 2);
    acc += __shfl_xor(acc, 4);
    acc += __shfl_xor(acc, 8);
    if (kg == 0) g_lds[r_local] = acc + brow;
    __syncthreads();                                  // sync 4

    if (tid < UPW) {
      float iv = g_lds[tid], fv = g_lds[8 + tid], gv = g_lds[16 + tid], ov = g_lds[24 + tid];
      float c_new = sigmoidf_(fv) * c_state[tid] + sigmoidf_(iv) * tanhf(gv);
      float h_new = sigmoidf_(ov) * tanhf(c_new);
      c_state[tid] = c_new;
      h_tmp[tid] = h_new;
      out[(size_t)t * H + wg * UPW + tid] = h_new;
    }

    // ---- publish h (packed half) + grid barrier, inlined ----
    __syncthreads();                                  // sync 5 (h_tmp ready)
    if (tid < 4) {
      unsigned int pk =
          (unsigned int)__half_as_ushort(__float2half_rn(h_tmp[tid * 2])) |
          ((unsigned int)__half_as_ushort(__float2half_rn(h_tmp[tid * 2 + 1])) << 16);
      AT_STU(hGu + wg * 4 + tid, pk);
    }
    ++ep;
    if (wg == 0) {
      if (tid > 0 && tid < NWG) {
        while (AT_LDI(&flags[tid * 32]) < ep) __builtin_amdgcn_s_sleep(2);
      }
      __syncthreads();                                // sync 6
      if (tid == 0)
        __hip_atomic_store(genp, ep, __ATOMIC_RELEASE, __HIP_MEMORY_SCOPE_SYSTEM);
    } else {
      if (tid == 0) {
        __hip_atomic_store(&flags[wg * 32], ep, __ATOMIC_RELEASE, __HIP_MEMORY_SCOPE_SYSTEM);
        while (AT_LDI(genp) < ep) __builtin_amdgcn_s_sleep(2);
      }
      __syncthreads();                                // sync 6
    }
  }
}

extern "C" void kernel_launch(void* const* d_in, const int* in_sizes, int n_in,
                              void* d_out, int out_size, void* d_ws, size_t ws_size,
                              hipStream_t stream) {
  const float* input    = (const float*)d_in[0];
  const float* bias_mat = (const float*)d_in[1];
  const float* conv_w   = (const float*)d_in[2];
  const float* conv_b   = (const float*)d_in[3];
  const float* fc1_w    = (const float*)d_in[4];
  const float* fc1_b    = (const float*)d_in[5];
  const float* w_ih     = (const float*)d_in[6];
  const float* b_ih     = (const float*)d_in[7];
  const float* w_hh     = (const float*)d_in[8];
  const float* b_hh     = (const float*)d_in[9];
  const int*   seqp     = (const int*)d_in[10];
  float* out = (float*)d_out;
  float* ws  = (float*)d_ws;

  const bool hw16 = (ws_size >= WS_NEED_BYTES);

  hipLaunchKernelGGL(init_ws, dim3(1), dim3(1024), 0, stream, ws);
  hipLaunchKernelGGL(gemm_P, dim3(64, 4), dim3(256), 0, stream,
                     w_ih, input, (__half*)(ws + WS_PH));
  if (hw16) {
    hipLaunchKernelGGL(whh_to_half, dim3(8192), dim3(256), 0, stream,
                       w_hh, (__half*)(ws + WS_WHH));
    hipLaunchKernelGGL(attn_rnn_main<true>, dim3(NWG), dim3(TPB), 0, stream,
                       input, bias_mat, conv_w, conv_b, fc1_w, fc1_b,
                       w_hh, b_ih, b_hh, seqp, out, ws);
  } else {
    hipLaunchKernelGGL(attn_rnn_main<false>, dim3(NWG), dim3(TPB), 0, stream,
                       input, bias_mat, conv_w, conv_b, fc1_w, fc1_b,
                       w_hh, b_ih, b_hh, seqp, out, ws);
  }
}

// Round 8
// 3721.721 us; speedup vs baseline: 1.8007x; 1.8007x over previous
//
#include <hip/hip_runtime.h>
#include <hip/hip_fp16.h>

#define H     2048
#define LSEQ  512
#define NWG   256
#define TPB   512
#define UPW   8     // hidden units per WG
#define RPW   32    // gate rows per WG
#define KG    16    // k-groups per row

// ws float-index layout
#define WS_UA    0        // 512 floats
#define WS_HG    512      // 512 u64 = 2048 packed halfs (h state) -> 1024 float slots
#define WS_GEN   1600     // 1 int
#define WS_FLAGS 1664     // 256*32 ints (128B-padded arrival flags)
#define WS_P     16384    // fp32 P: 8192*512 floats = 16 MB

typedef unsigned long long u64;

#define AT_LDF(p)    __hip_atomic_load((p),  __ATOMIC_RELAXED, __HIP_MEMORY_SCOPE_SYSTEM)
#define AT_STF(p, v) __hip_atomic_store((p), (v), __ATOMIC_RELAXED, __HIP_MEMORY_SCOPE_SYSTEM)
#define AT_LDI(p)    __hip_atomic_load((p),  __ATOMIC_RELAXED, __HIP_MEMORY_SCOPE_SYSTEM)
#define AT_LD64(p)   __hip_atomic_load((p),  __ATOMIC_RELAXED, __HIP_MEMORY_SCOPE_SYSTEM)
#define AT_ST64(p,v) __hip_atomic_store((p), (v), __ATOMIC_RELAXED, __HIP_MEMORY_SCOPE_SYSTEM)

__device__ __forceinline__ float sigmoidf_(float v) { return 1.f / (1.f + __expf(-v)); }

#if defined(__has_builtin)
#if __has_builtin(__builtin_amdgcn_fdot2)
#define HAVE_FDOT2 1
#endif
#endif
typedef _Float16 hh2 __attribute__((ext_vector_type(2)));

// c += dot(half2 a, half2 b)
__device__ __forceinline__ float dot2acc(unsigned int a, unsigned int b, float c) {
#ifdef HAVE_FDOT2
  return __builtin_amdgcn_fdot2(__builtin_bit_cast(hh2, a), __builtin_bit_cast(hh2, b), c, false);
#else
  float2 af = __half22float2(*(__half2*)&a);
  float2 bf = __half22float2(*(__half2*)&b);
  return c + af.x * bf.x + af.y * bf.y;
#endif
}

__global__ void init_ws(float* ws) {
  int tid = threadIdx.x;
  for (int i = tid; i < 1024; i += 1024) ((unsigned int*)(ws + WS_HG))[i] = 0u;  // h0 = 0 (fp16 zeros)
  int* gen = (int*)(ws + WS_GEN);
  int* flags = (int*)(ws + WS_FLAGS);
  if (tid == 0) *gen = 0;
  for (int i = tid; i < NWG * 32; i += 1024) flags[i] = 0;
}

// ---- one-time P = W_ih @ input^T (fp32)  ([8192,2048]x[512,2048]^T -> [8192,512]) ----
#define GP_BM 128
#define GP_BN 128
#define GP_BK 32
#define GP_PAD 5
__global__ __launch_bounds__(256) void gemm_P(const float* __restrict__ A,
                                              const float* __restrict__ B,
                                              float* __restrict__ P) {
  __shared__ float As[GP_BM][GP_BK + GP_PAD];
  __shared__ float Bs[GP_BN][GP_BK + GP_PAD];
  const int tid = threadIdx.x;
  const int bm = blockIdx.x, bn = blockIdx.y;
  const int tr = tid >> 4, tc = tid & 15;
  float acc[8][8] = {};
  for (int k0 = 0; k0 < H; k0 += GP_BK) {
    #pragma unroll
    for (int i = 0; i < 4; ++i) {
      int lin = tid + 256 * i;
      int r = lin >> 3, c4 = lin & 7;
      float4 va = *(const float4*)(A + (size_t)(bm * GP_BM + r) * H + k0 + c4 * 4);
      float4 vb = *(const float4*)(B + (size_t)(bn * GP_BN + r) * H + k0 + c4 * 4);
      As[r][c4 * 4 + 0] = va.x; As[r][c4 * 4 + 1] = va.y;
      As[r][c4 * 4 + 2] = va.z; As[r][c4 * 4 + 3] = va.w;
      Bs[r][c4 * 4 + 0] = vb.x; Bs[r][c4 * 4 + 1] = vb.y;
      Bs[r][c4 * 4 + 2] = vb.z; Bs[r][c4 * 4 + 3] = vb.w;
    }
    __syncthreads();
    #pragma unroll 8
    for (int k = 0; k < GP_BK; ++k) {
      float a[8], b[8];
      #pragma unroll
      for (int i = 0; i < 8; ++i) a[i] = As[tr * 8 + i][k];
      #pragma unroll
      for (int j = 0; j < 8; ++j) b[j] = Bs[tc * 8 + j][k];
      #pragma unroll
      for (int i = 0; i < 8; ++i)
        #pragma unroll
        for (int j = 0; j < 8; ++j) acc[i][j] += a[i] * b[j];
    }
    __syncthreads();
  }
  #pragma unroll
  for (int i = 0; i < 8; ++i)
    #pragma unroll
    for (int j4 = 0; j4 < 2; ++j4) {
      float4 v = make_float4(acc[i][j4 * 4], acc[i][j4 * 4 + 1],
                             acc[i][j4 * 4 + 2], acc[i][j4 * 4 + 3]);
      *(float4*)(P + (size_t)(bm * GP_BM + tr * 8 + i) * LSEQ + bn * GP_BN + tc * 8 + j4 * 4) = v;
    }
}

// ---------------- persistent main kernel: weights register-resident fp16 ----------------
__global__ __launch_bounds__(TPB, 1) void attn_rnn_main(
    const float* __restrict__ input, const float* __restrict__ bias_mat,
    const float* __restrict__ conv_w, const float* __restrict__ conv_b,
    const float* __restrict__ fc1_w, const float* __restrict__ fc1_b,
    const float* __restrict__ w_hh, const float* __restrict__ b_ih,
    const float* __restrict__ b_hh,
    const int* __restrict__ seq_len,
    float* __restrict__ out, float* __restrict__ ws)
{
  const int wg   = blockIdx.x;
  const int tid  = threadIdx.x;
  const int lane = tid & 63;
  const int wv   = tid >> 6;   // 0..7

  float* uaG   = ws + WS_UA;
  u64*   hG64  = (u64*)(ws + WS_HG);
  int*   genp  = (int*)(ws + WS_GEN);
  int*   flags = (int*)(ws + WS_FLAGS);
  const float* Pf = ws + WS_P;

  __shared__ unsigned int h_u[1024];   // h as packed half2
  __shared__ float attn_lds[LSEQ];
  __shared__ float ua_lds[LSEQ];
  __shared__ float b_lds[LSEQ];
  __shared__ float g_lds[RPW];
  __shared__ float red8[8];
  __shared__ float redm[8];
  __shared__ float reds[8];
  __shared__ float c_state[UPW];
  __shared__ float h_tmp[UPW];

  const int r_local = tid >> 4;       // 0..31 gate row within WG
  const int kg      = tid & 15;       // 0..15 k-group
  const int gt      = r_local >> 3;
  const int u       = r_local & 7;
  const int rg      = gt * H + wg * UPW + u;
  const float brow  = b_ih[rg] + b_hh[rg];

  // ---- ONE-TIME: weights -> registers as packed fp16 (statically indexed) ----
  // thread (r_local,kg) owns columns j = jj*16+kg (half2 granularity).
  unsigned int w_u[64];
  #pragma unroll
  for (int jj = 0; jj < 64; ++jj) {
    float2 wvv = *(const float2*)(w_hh + (size_t)rg * H + 2 * (jj * 16 + kg));
    __half2 p = __floats2half2_rn(wvv.x, wvv.y);
    w_u[jj] = *(unsigned int*)&p;
  }
  unsigned int p_u[16];
  #pragma unroll
  for (int jj = 0; jj < 16; ++jj) {
    float2 pvv = *(const float2*)(Pf + (size_t)rg * LSEQ + 2 * (jj * 16 + kg));
    __half2 p = __floats2half2_rn(pvv.x, pvv.y);
    p_u[jj] = *(unsigned int*)&p;
  }
  #pragma unroll
  for (int jj = 0; jj < 64; ++jj) asm volatile("" : "+v"(w_u[jj]));
  #pragma unroll
  for (int jj = 0; jj < 16; ++jj) asm volatile("" : "+v"(p_u[jj]));

  const float4 fw4 = ((const float4*)fc1_w)[tid];
  if (tid < UPW) c_state[tid] = 0.f;

  int ep = 0;

  // ---- ua[l] = input[l,:]·conv_w + conv_b  (WG owns l = 2wg, 2wg+1) ----
  const float cb = conv_b[0];
  #pragma unroll
  for (int li = 0; li < 2; ++li) {
    int l = wg * 2 + li;
    float4 rv = ((const float4*)(input + (size_t)l * H))[tid];
    float4 cv = ((const float4*)conv_w)[tid];
    float s = rv.x * cv.x + rv.y * cv.y + rv.z * cv.z + rv.w * cv.w;
    #pragma unroll
    for (int m = 32; m; m >>= 1) s += __shfl_xor(s, m);
    if (lane == 0) red8[wv] = s;
    __syncthreads();
    if (tid == 0) {
      float v = cb;
      #pragma unroll
      for (int q = 0; q < 8; ++q) v += red8[q];
      AT_STF(&uaG[l], v);
    }
    __syncthreads();
  }

  // prologue grid barrier
  ++ep;
  if (wg == 0) {
    if (tid > 0 && tid < NWG) {
      while (AT_LDI(&flags[tid * 32]) < ep) __builtin_amdgcn_s_sleep(2);
    }
    __syncthreads();
    if (tid == 0) __hip_atomic_store(genp, ep, __ATOMIC_RELEASE, __HIP_MEMORY_SCOPE_SYSTEM);
  } else {
    if (tid == 0) {
      __hip_atomic_store(&flags[wg * 32], ep, __ATOMIC_RELEASE, __HIP_MEMORY_SCOPE_SYSTEM);
      while (AT_LDI(genp) < ep) __builtin_amdgcn_s_sleep(2);
    }
    __syncthreads();
  }

  // step-invariant terms into LDS
  ua_lds[tid & (LSEQ - 1)] = AT_LDF(&uaG[tid & (LSEQ - 1)]);
  b_lds[tid & (LSEQ - 1)]  = bias_mat[tid & (LSEQ - 1)];
  __syncthreads();

  const int S = seq_len[0];
  const float fb = fc1_b[0];

  for (int t = 0; t < S; ++t) {
    // ---- phase 1: h (packed fp16, MALL-coherent) -> LDS; fc1 partial dot ----
    u64 hv = AT_LD64(hG64 + tid);
    unsigned int lo = (unsigned int)hv, hi = (unsigned int)(hv >> 32);
    h_u[2 * tid]     = lo;
    h_u[2 * tid + 1] = hi;
    float2 f01 = __half22float2(*(__half2*)&lo);
    float2 f23 = __half22float2(*(__half2*)&hi);
    float s = f01.x * fw4.x + f01.y * fw4.y + f23.x * fw4.z + f23.y * fw4.w;
    #pragma unroll
    for (int m = 32; m; m >>= 1) s += __shfl_xor(s, m);
    if (lane == 0) red8[wv] = s;
    __syncthreads();                                  // sync 1

    // ---- phase 2: w_a, logits, wave-local softmax stats; overlap whh GEMV ----
    float w_a = fb;
    #pragma unroll
    for (int q = 0; q < 8; ++q) w_a += red8[q];       // redundant, deterministic
    float v0 = ua_lds[tid] + w_a;
    float v = v0 > 0.f ? v0 : 0.01f * v0;             // leaky_relu(0.01)
    v += b_lds[tid];
    float mw = v;
    #pragma unroll
    for (int m = 32; m; m >>= 1) mw = fmaxf(mw, __shfl_xor(mw, m));
    float eW = __expf(v - mw);
    float sw = eW;
    #pragma unroll
    for (int m = 32; m; m >>= 1) sw += __shfl_xor(sw, m);
    if (lane == 0) { redm[wv] = mw; reds[wv] = sw; }

    // whh·h from registers (independent of softmax -> fills the wait)
    float acch = 0.f;
    #pragma unroll
    for (int jj = 0; jj < 64; ++jj)
      acch = dot2acc(w_u[jj], h_u[jj * 16 + kg], acch);
    __syncthreads();                                  // sync 2

    // ---- phase 3: combine softmax stats; write attn ----
    float M = redm[0];
    #pragma unroll
    for (int q = 1; q < 8; ++q) M = fmaxf(M, redm[q]);
    float Ssum = 0.f;
    #pragma unroll
    for (int q = 0; q < 8; ++q) Ssum += reds[q] * __expf(redm[q] - M);
    const float inv = 1.f / Ssum;
    attn_lds[tid] = eW * __expf(mw - M);
    __syncthreads();                                  // sync 3

    // ---- phase 4: P·attn from registers; reduce over kg ----
    float accp = 0.f;
    #pragma unroll
    for (int jj = 0; jj < 16; ++jj) {
      float2 af = *(const float2*)(attn_lds + 2 * (jj * 16 + kg));
      float2 pf = __half22float2(*(__half2*)&p_u[jj]);
      accp += pf.x * af.x + pf.y * af.y;
    }
    float acc = acch + accp * inv;
    acc += __shfl_xor(acc, 1);
    acc += __shfl_xor(acc, 2);
    acc += __shfl_xor(acc, 4);
    acc += __shfl_xor(acc, 8);
    if (kg == 0) g_lds[r_local] = acc + brow;
    __syncthreads();                                  // sync 4

    // ---- phase 5: LSTM (lanes 0..7, wave 0); pack+publish h; grid barrier ----
    if (tid < UPW) {
      float iv = g_lds[tid], fv = g_lds[8 + tid], gv = g_lds[16 + tid], ov = g_lds[24 + tid];
      float c_new = sigmoidf_(fv) * c_state[tid] + sigmoidf_(iv) * tanhf(gv);
      float h_new = sigmoidf_(ov) * tanhf(c_new);
      c_state[tid] = c_new;
      h_tmp[tid] = h_new;
      out[(size_t)t * H + wg * UPW + tid] = h_new;
    }
    // same wave (lanes 0..7 wrote h_tmp; lanes 0..1 read) -> no sync needed
    if (tid < 2) {
      __half2 a = __floats2half2_rn(h_tmp[tid * 4 + 0], h_tmp[tid * 4 + 1]);
      __half2 b = __floats2half2_rn(h_tmp[tid * 4 + 2], h_tmp[tid * 4 + 3]);
      u64 pk = (u64)(*(unsigned int*)&a) | ((u64)(*(unsigned int*)&b) << 32);
      AT_ST64(hG64 + wg * 2 + tid, pk);
    }
    ++ep;
    if (wg == 0) {
      if (tid > 0 && tid < NWG) {
        while (AT_LDI(&flags[tid * 32]) < ep) __builtin_amdgcn_s_sleep(2);
      }
      __syncthreads();                                // sync 5
      if (tid == 0)
        __hip_atomic_store(genp, ep, __ATOMIC_RELEASE, __HIP_MEMORY_SCOPE_SYSTEM);
    } else {
      if (tid == 0) {
        __hip_atomic_store(&flags[wg * 32], ep, __ATOMIC_RELEASE, __HIP_MEMORY_SCOPE_SYSTEM);
        while (AT_LDI(genp) < ep) __builtin_amdgcn_s_sleep(2);
      }
      __syncthreads();                                // sync 5
    }
  }
}

extern "C" void kernel_launch(void* const* d_in, const int* in_sizes, int n_in,
                              void* d_out, int out_size, void* d_ws, size_t ws_size,
                              hipStream_t stream) {
  const float* input    = (const float*)d_in[0];
  const float* bias_mat = (const float*)d_in[1];
  const float* conv_w   = (const float*)d_in[2];
  const float* conv_b   = (const float*)d_in[3];
  const float* fc1_w    = (const float*)d_in[4];
  const float* fc1_b    = (const float*)d_in[5];
  const float* w_ih     = (const float*)d_in[6];
  const float* b_ih     = (const float*)d_in[7];
  const float* w_hh     = (const float*)d_in[8];
  const float* b_hh     = (const float*)d_in[9];
  const int*   seqp     = (const int*)d_in[10];
  float* out = (float*)d_out;
  float* ws  = (float*)d_ws;

  hipLaunchKernelGGL(init_ws, dim3(1), dim3(1024), 0, stream, ws);
  hipLaunchKernelGGL(gemm_P, dim3(64, 4), dim3(256), 0, stream, w_ih, input, ws + WS_P);
  hipLaunchKernelGGL(attn_rnn_main, dim3(NWG), dim3(TPB), 0, stream,
                     input, bias_mat, conv_w, conv_b, fc1_w, fc1_b,
                     w_hh, b_ih, b_hh, seqp, out, ws);
}

// Round 9
// 3322.540 us; speedup vs baseline: 2.0170x; 1.1201x over previous
//
#include <hip/hip_runtime.h>
#include <hip/hip_fp16.h>

#define H     2048
#define LSEQ  512
#define NWG   256
#define TPB   512
#define UPW   8     // hidden units per WG
#define RPW   32    // gate rows per WG
#define KG    16    // k-groups per row

// ws float-index layout
#define WS_UA    0        // 512 floats
#define WS_HPUB  512      // 2 slots x 1024 u64 (epoch-tagged h half2) = 4096 floats
#define WS_GEN   4608     // 1 int (prologue barrier)
#define WS_FLAGS 4672     // 256*32 ints (prologue barrier flags)
#define WS_P     16384    // fp32 P: 8192*512 floats = 16 MB

typedef unsigned long long u64;

#define AT_LDF(p)    __hip_atomic_load((p),  __ATOMIC_RELAXED, __HIP_MEMORY_SCOPE_SYSTEM)
#define AT_STF(p, v) __hip_atomic_store((p), (v), __ATOMIC_RELAXED, __HIP_MEMORY_SCOPE_SYSTEM)
#define AT_LDI(p)    __hip_atomic_load((p),  __ATOMIC_RELAXED, __HIP_MEMORY_SCOPE_SYSTEM)
#define AT_LD64(p)   __hip_atomic_load((p),  __ATOMIC_RELAXED, __HIP_MEMORY_SCOPE_SYSTEM)
#define AT_ST64(p,v) __hip_atomic_store((p), (v), __ATOMIC_RELAXED, __HIP_MEMORY_SCOPE_SYSTEM)

__device__ __forceinline__ float sigmoidf_(float v) { return 1.f / (1.f + __expf(-v)); }

#if defined(__has_builtin)
#if __has_builtin(__builtin_amdgcn_fdot2)
#define HAVE_FDOT2 1
#endif
#endif
typedef _Float16 hh2 __attribute__((ext_vector_type(2)));

// c += dot(half2 a, half2 b)
__device__ __forceinline__ float dot2acc(unsigned int a, unsigned int b, float c) {
#ifdef HAVE_FDOT2
  return __builtin_amdgcn_fdot2(__builtin_bit_cast(hh2, a), __builtin_bit_cast(hh2, b), c, false);
#else
  float2 af = __half22float2(*(__half2*)&a);
  float2 bf = __half22float2(*(__half2*)&b);
  return c + af.x * bf.x + af.y * bf.y;
#endif
}

__global__ void init_ws(float* ws) {
  int tid = threadIdx.x;
  u64* hPub = (u64*)(ws + WS_HPUB);
  for (int i = tid; i < 2048; i += 1024) hPub[i] = 0ull;  // tag=0, h=0 (both slots)
  int* gen = (int*)(ws + WS_GEN);
  int* flags = (int*)(ws + WS_FLAGS);
  if (tid == 0) *gen = 0;
  for (int i = tid; i < NWG * 32; i += 1024) flags[i] = 0;
}

// ---- one-time P = W_ih @ input^T (fp32)  ([8192,2048]x[512,2048]^T -> [8192,512]) ----
#define GP_BM 128
#define GP_BN 128
#define GP_BK 32
#define GP_PAD 5
__global__ __launch_bounds__(256) void gemm_P(const float* __restrict__ A,
                                              const float* __restrict__ B,
                                              float* __restrict__ P) {
  __shared__ float As[GP_BM][GP_BK + GP_PAD];
  __shared__ float Bs[GP_BN][GP_BK + GP_PAD];
  const int tid = threadIdx.x;
  const int bm = blockIdx.x, bn = blockIdx.y;
  const int tr = tid >> 4, tc = tid & 15;
  float acc[8][8] = {};
  for (int k0 = 0; k0 < H; k0 += GP_BK) {
    #pragma unroll
    for (int i = 0; i < 4; ++i) {
      int lin = tid + 256 * i;
      int r = lin >> 3, c4 = lin & 7;
      float4 va = *(const float4*)(A + (size_t)(bm * GP_BM + r) * H + k0 + c4 * 4);
      float4 vb = *(const float4*)(B + (size_t)(bn * GP_BN + r) * H + k0 + c4 * 4);
      As[r][c4 * 4 + 0] = va.x; As[r][c4 * 4 + 1] = va.y;
      As[r][c4 * 4 + 2] = va.z; As[r][c4 * 4 + 3] = va.w;
      Bs[r][c4 * 4 + 0] = vb.x; Bs[r][c4 * 4 + 1] = vb.y;
      Bs[r][c4 * 4 + 2] = vb.z; Bs[r][c4 * 4 + 3] = vb.w;
    }
    __syncthreads();
    #pragma unroll 8
    for (int k = 0; k < GP_BK; ++k) {
      float a[8], b[8];
      #pragma unroll
      for (int i = 0; i < 8; ++i) a[i] = As[tr * 8 + i][k];
      #pragma unroll
      for (int j = 0; j < 8; ++j) b[j] = Bs[tc * 8 + j][k];
      #pragma unroll
      for (int i = 0; i < 8; ++i)
        #pragma unroll
        for (int j = 0; j < 8; ++j) acc[i][j] += a[i] * b[j];
    }
    __syncthreads();
  }
  #pragma unroll
  for (int i = 0; i < 8; ++i)
    #pragma unroll
    for (int j4 = 0; j4 < 2; ++j4) {
      float4 v = make_float4(acc[i][j4 * 4], acc[i][j4 * 4 + 1],
                             acc[i][j4 * 4 + 2], acc[i][j4 * 4 + 3]);
      *(float4*)(P + (size_t)(bm * GP_BM + tr * 8 + i) * LSEQ + bn * GP_BN + tc * 8 + j4 * 4) = v;
    }
}

// ---------------- persistent main kernel ----------------
__global__ __launch_bounds__(TPB, 1) void attn_rnn_main(
    const float* __restrict__ input, const float* __restrict__ bias_mat,
    const float* __restrict__ conv_w, const float* __restrict__ conv_b,
    const float* __restrict__ fc1_w, const float* __restrict__ fc1_b,
    const float* __restrict__ w_hh, const float* __restrict__ b_ih,
    const float* __restrict__ b_hh,
    const int* __restrict__ seq_len,
    float* __restrict__ out, float* __restrict__ ws)
{
  const int wg   = blockIdx.x;
  const int tid  = threadIdx.x;
  const int lane = tid & 63;
  const int wv   = tid >> 6;   // 0..7

  float* uaG   = ws + WS_UA;
  u64*   hPub  = (u64*)(ws + WS_HPUB);   // [2][1024] epoch-tagged half2 words
  int*   genp  = (int*)(ws + WS_GEN);
  int*   flags = (int*)(ws + WS_FLAGS);
  const float* Pf = ws + WS_P;

  __shared__ unsigned int h_u[1024];   // h as packed half2
  __shared__ float ua_lds[LSEQ];
  __shared__ float b_lds[LSEQ];
  __shared__ float g_lds[RPW];
  __shared__ float redm[8];
  __shared__ float reds[8];
  __shared__ float c_state[UPW];
  __shared__ float h_tmp[UPW];

  const int r_local = tid >> 4;       // 0..31 gate row within WG
  const int kg      = tid & 15;       // 0..15 k-group
  const int gt      = r_local >> 3;
  const int u       = r_local & 7;
  const int rg      = gt * H + wg * UPW + u;
  const float brow  = b_ih[rg] + b_hh[rg];

  // ---- ONE-TIME: weights -> registers as packed fp16 (statically indexed) ----
  unsigned int w_u[64];
  #pragma unroll
  for (int jj = 0; jj < 64; ++jj) {
    float2 wvv = *(const float2*)(w_hh + (size_t)rg * H + 2 * (jj * 16 + kg));
    __half2 p = __floats2half2_rn(wvv.x, wvv.y);
    w_u[jj] = *(unsigned int*)&p;
  }
  unsigned int p_u[16];
  #pragma unroll
  for (int jj = 0; jj < 16; ++jj) {
    float2 pvv = *(const float2*)(Pf + (size_t)rg * LSEQ + 2 * (jj * 16 + kg));
    __half2 p = __floats2half2_rn(pvv.x, pvv.y);
    p_u[jj] = *(unsigned int*)&p;
  }
  #pragma unroll
  for (int jj = 0; jj < 64; ++jj) asm volatile("" : "+v"(w_u[jj]));
  #pragma unroll
  for (int jj = 0; jj < 16; ++jj) asm volatile("" : "+v"(p_u[jj]));

  if (tid < UPW) c_state[tid] = 0.f;

  // ---- ua[l] = input[l,:]·conv_w + conv_b  (WG owns l = 2wg, 2wg+1) ----
  const float cb = conv_b[0];
  {
    __shared__ float red8p[8];
    #pragma unroll
    for (int li = 0; li < 2; ++li) {
      int l = wg * 2 + li;
      float4 rv = ((const float4*)(input + (size_t)l * H))[tid];
      float4 cv = ((const float4*)conv_w)[tid];
      float s = rv.x * cv.x + rv.y * cv.y + rv.z * cv.z + rv.w * cv.w;
      #pragma unroll
      for (int m = 32; m; m >>= 1) s += __shfl_xor(s, m);
      if (lane == 0) red8p[wv] = s;
      __syncthreads();
      if (tid == 0) {
        float v = cb;
        #pragma unroll
        for (int q = 0; q < 8; ++q) v += red8p[q];
        AT_STF(&uaG[l], v);
      }
      __syncthreads();
    }
  }

  // prologue grid barrier (flag/gen, one-time)
  {
    const int ep = 1;
    if (wg == 0) {
      if (tid > 0 && tid < NWG) {
        while (AT_LDI(&flags[tid * 32]) < ep) __builtin_amdgcn_s_sleep(2);
      }
      __syncthreads();
      if (tid == 0) __hip_atomic_store(genp, ep, __ATOMIC_RELEASE, __HIP_MEMORY_SCOPE_SYSTEM);
    } else {
      if (tid == 0) {
        __hip_atomic_store(&flags[wg * 32], ep, __ATOMIC_RELEASE, __HIP_MEMORY_SCOPE_SYSTEM);
        while (AT_LDI(genp) < ep) __builtin_amdgcn_s_sleep(2);
      }
      __syncthreads();
    }
  }

  // step-invariant terms into LDS
  ua_lds[tid & (LSEQ - 1)] = AT_LDF(&uaG[tid & (LSEQ - 1)]);
  b_lds[tid & (LSEQ - 1)]  = bias_mat[tid & (LSEQ - 1)];
  const float4 fw4 = ((const float4*)fc1_w)[tid & 511];   // kept for symmetry (unused path)
  (void)fw4;

  const int S = seq_len[0];
  const float fb = fc1_b[0];

  // poll assignment: thread i watches WG (i>>1), word pair (i&1)*2
  const int pwg  = tid >> 1;
  const int pidx = pwg * 4 + (tid & 1) * 2;

  __syncthreads();   // ua_lds/b_lds ready

  for (int t = 0; t < S; ++t) {
    // ---- single-hop rendezvous: poll epoch-tagged h words, deposit into LDS ----
    {
      const u64* slot = hPub + (size_t)(t & 1) * 1024;
      u64 a = AT_LD64(slot + pidx);
      u64 b = AT_LD64(slot + pidx + 1);
      while ((int)(a >> 32) < t || (int)(b >> 32) < t) {
        __builtin_amdgcn_s_sleep(1);
        a = AT_LD64(slot + pidx);
        b = AT_LD64(slot + pidx + 1);
      }
      h_u[pidx]     = (unsigned int)a;
      h_u[pidx + 1] = (unsigned int)b;
    }
    __syncthreads();                                  // S1: h in LDS

    // ---- fc1 dot, per-wave redundant (identical order -> identical w_a) ----
    float s = 0.f;
    #pragma unroll
    for (int q = 0; q < 16; ++q) {
      unsigned int hw = h_u[lane + 64 * q];           // conflict-free: bank = lane%32
      float2 hf = __half22float2(*(__half2*)&hw);
      float2 ff = *(const float2*)(fc1_w + 2 * (lane + 64 * q));
      s += hf.x * ff.x + hf.y * ff.y;
    }
    #pragma unroll
    for (int m = 32; m; m >>= 1) s += __shfl_xor(s, m);
    const float w_a = fb + s;                          // uniform across block

    // ---- softmax wave stats ----
    float v0 = ua_lds[tid] + w_a;
    float v = v0 > 0.f ? v0 : 0.01f * v0;             // leaky_relu(0.01)
    v += b_lds[tid];
    float mw = v;
    #pragma unroll
    for (int m = 32; m; m >>= 1) mw = fmaxf(mw, __shfl_xor(mw, m));
    float eW = __expf(v - mw);
    float sw = eW;
    #pragma unroll
    for (int m = 32; m; m >>= 1) sw += __shfl_xor(sw, m);
    if (lane == 0) { redm[wv] = mw; reds[wv] = sw; }

    // ---- whh·h from registers (independent -> fills the sync wait) ----
    float a0 = 0.f, a1 = 0.f, a2 = 0.f, a3 = 0.f;
    #pragma unroll
    for (int jj = 0; jj < 16; ++jj) {
      a0 = dot2acc(w_u[4 * jj + 0], h_u[(4 * jj + 0) * 16 + kg], a0);
      a1 = dot2acc(w_u[4 * jj + 1], h_u[(4 * jj + 1) * 16 + kg], a1);
      a2 = dot2acc(w_u[4 * jj + 2], h_u[(4 * jj + 2) * 16 + kg], a2);
      a3 = dot2acc(w_u[4 * jj + 3], h_u[(4 * jj + 3) * 16 + kg], a3);
    }
    float acch = (a0 + a1) + (a2 + a3);
    __syncthreads();                                  // S2: redm/reds ready

    // ---- combine stats (redundant per thread); P·attn with inline attn ----
    float M = redm[0];
    #pragma unroll
    for (int q = 1; q < 8; ++q) M = fmaxf(M, redm[q]);
    float Ssum = 0.f;
    #pragma unroll
    for (int q = 0; q < 8; ++q) Ssum += reds[q] * __expf(redm[q] - M);
    const float inv = 1.f / Ssum;

    float accp = 0.f;
    #pragma unroll
    for (int jj = 0; jj < 16; ++jj) {
      const int l0 = 2 * (jj * 16 + kg);
      float u0 = ua_lds[l0] + w_a;
      float u1 = ua_lds[l0 + 1] + w_a;
      u0 = (u0 > 0.f ? u0 : 0.01f * u0) + b_lds[l0];
      u1 = (u1 > 0.f ? u1 : 0.01f * u1) + b_lds[l0 + 1];
      float e0 = __expf(u0 - M);
      float e1 = __expf(u1 - M);
      float2 pf = __half22float2(*(__half2*)&p_u[jj]);
      accp += pf.x * e0 + pf.y * e1;
    }
    float acc = acch + accp * inv;
    acc += __shfl_xor(acc, 1);
    acc += __shfl_xor(acc, 2);
    acc += __shfl_xor(acc, 4);
    acc += __shfl_xor(acc, 8);
    if (kg == 0) g_lds[r_local] = acc + brow;
    __syncthreads();                                  // S3: gates ready

    // ---- LSTM (wave 0) + epoch-tagged publish ----
    if (tid < UPW) {
      float iv = g_lds[tid], fv = g_lds[8 + tid], gv = g_lds[16 + tid], ov = g_lds[24 + tid];
      float c_new = sigmoidf_(fv) * c_state[tid] + sigmoidf_(iv) * tanhf(gv);
      float h_new = sigmoidf_(ov) * tanhf(c_new);
      c_state[tid] = c_new;
      h_tmp[tid] = h_new;
      out[(size_t)t * H + wg * UPW + tid] = h_new;
    }
    if (tid < 4) {   // same wave as h_tmp writers -> no sync needed
      __half2 hp = __floats2half2_rn(h_tmp[2 * tid], h_tmp[2 * tid + 1]);
      u64 word = ((u64)(unsigned int)(t + 1) << 32) | (u64)(*(unsigned int*)&hp);
      AT_ST64(hPub + (size_t)((t + 1) & 1) * 1024 + wg * 4 + tid, word);
    }
    // no trailing sync: next iteration's poll is the barrier
  }
}

extern "C" void kernel_launch(void* const* d_in, const int* in_sizes, int n_in,
                              void* d_out, int out_size, void* d_ws, size_t ws_size,
                              hipStream_t stream) {
  const float* input    = (const float*)d_in[0];
  const float* bias_mat = (const float*)d_in[1];
  const float* conv_w   = (const float*)d_in[2];
  const float* conv_b   = (const float*)d_in[3];
  const float* fc1_w    = (const float*)d_in[4];
  const float* fc1_b    = (const float*)d_in[5];
  const float* w_ih     = (const float*)d_in[6];
  const float* b_ih     = (const float*)d_in[7];
  const float* w_hh     = (const float*)d_in[8];
  const float* b_hh     = (const float*)d_in[9];
  const int*   seqp     = (const int*)d_in[10];
  float* out = (float*)d_out;
  float* ws  = (float*)d_ws;

  hipLaunchKernelGGL(init_ws, dim3(1), dim3(1024), 0, stream, ws);
  hipLaunchKernelGGL(gemm_P, dim3(64, 4), dim3(256), 0, stream, w_ih, input, ws + WS_P);
  hipLaunchKernelGGL(attn_rnn_main, dim3(NWG), dim3(TPB), 0, stream,
                     input, bias_mat, conv_w, conv_b, fc1_w, fc1_b,
                     w_hh, b_ih, b_hh, seqp, out, ws);
}